// Round 1
// baseline (201.172 us; speedup 1.0000x reference)
//
#include <hip/hip_runtime.h>

#define NFFT 3072
#define THREADS 256
#define PER 12            // NFFT / THREADS
#define HOP 192
#define HALF 1536
#define TFRAMES 1000
#define OUTLEN 191808     // (TFRAMES-1)*HOP
#define NBANDS 128

__device__ __forceinline__ float2 cadd(float2 a, float2 b){ return make_float2(a.x+b.x, a.y+b.y); }
__device__ __forceinline__ float2 csub(float2 a, float2 b){ return make_float2(a.x-b.x, a.y-b.y); }
__device__ __forceinline__ float2 cmul(float2 a, float2 b){
    return make_float2(fmaf(a.x, b.x, -a.y*b.y), fmaf(a.x, b.y, a.y*b.x));
}

// Stockham DIF radix-4 stage: current length NN, stride S. Input X, output Y.
// y[q + S*(4p+j)] = DFT4(a)_j * w_NN^{p*j},  a_l = X[q + S*(p + (NN/4)*l)]
template<int NN, int S>
__device__ __forceinline__ void stage4(const float2* __restrict__ X, float2* __restrict__ Y, int tid)
{
    constexpr int M = NN / 4;
    constexpr float TW = -2.0f * 3.14159265358979323846f / (float)NN;
    #pragma unroll
    for (int v = 0; v < (NFFT/4)/THREADS; ++v) {   // 3 iterations
        int idx = tid + v*THREADS;
        int q = idx % S;
        int p = idx / S;
        float2 a0 = X[q + S*(p      )];
        float2 a1 = X[q + S*(p +   M)];
        float2 a2 = X[q + S*(p + 2*M)];
        float2 a3 = X[q + S*(p + 3*M)];
        float2 e0 = cadd(a0, a2), e1 = csub(a0, a2);
        float2 o0 = cadd(a1, a3), o1 = csub(a1, a3);
        float2 y0 = cadd(e0, o0);
        float2 y2 = csub(e0, o0);
        float2 io1 = make_float2(-o1.y, o1.x);     // i*(a1-a3)
        float2 y1 = csub(e1, io1);
        float2 y3 = cadd(e1, io1);
        float sw, cw;
        __sincosf(TW * (float)p, &sw, &cw);
        float2 w1 = make_float2(cw, sw);
        float2 w2 = cmul(w1, w1);
        float2 w3 = cmul(w2, w1);
        Y[q + S*(4*p    )] = y0;
        Y[q + S*(4*p + 1)] = cmul(y1, w1);
        Y[q + S*(4*p + 2)] = cmul(y2, w2);
        Y[q + S*(4*p + 3)] = cmul(y3, w3);
    }
}

// Stockham DIF radix-3 first stage: NN=3072, S=1.
__device__ __forceinline__ void stage3(const float2* __restrict__ X, float2* __restrict__ Y, int tid)
{
    const int M = 1024;
    const float TW = -2.0f * 3.14159265358979323846f / 3072.0f;
    const float S3 = -0.86602540378443864676f;   // Im(w3) = -sqrt(3)/2
    #pragma unroll
    for (int v = 0; v < 1024/THREADS; ++v) {     // 4 iterations
        int p = tid + v*THREADS;
        float2 a0 = X[p];
        float2 a1 = X[p +   M];
        float2 a2 = X[p + 2*M];
        float2 s12 = cadd(a1, a2);
        float2 d12 = csub(a1, a2);
        float2 y0 = cadd(a0, s12);
        float2 t  = make_float2(a0.x - 0.5f*s12.x, a0.y - 0.5f*s12.y);
        float2 isd = make_float2(-S3*d12.y, S3*d12.x);   // i*S3*(a1-a2)
        float2 y1 = cadd(t, isd);
        float2 y2 = csub(t, isd);
        float sw, cw;
        __sincosf(TW * (float)p, &sw, &cw);
        float2 w1 = make_float2(cw, sw);
        float2 w2 = cmul(w1, w1);
        Y[3*p    ] = y0;
        Y[3*p + 1] = cmul(y1, w1);
        Y[3*p + 2] = cmul(y2, w2);
    }
}

__global__ __launch_bounds__(THREADS)
void filtered_noise_kernel(const float* __restrict__ fb,
                           const float* __restrict__ noise,
                           float* __restrict__ out)
{
    __shared__ float2 A[NFFT];
    __shared__ float2 Bb[NFFT];
    __shared__ float gf[2*NBANDS];

    const int tid = threadIdx.x;
    const int wg  = blockIdx.x;
    const int b   = wg / (TFRAMES/2);
    const int tp  = wg % (TFRAMES/2);
    const int t0  = 2*tp;                 // frames t0 (real part) and t0+1 (imag part)

    const float* nz = noise + (size_t)b * OUTLEN;
    const int base0 = t0*HOP - HALF;      // padded-to-output index shift

    // Load two frames packed as complex. Frame t covers out-indices [t*HOP-HALF, +3072)
    #pragma unroll
    for (int v = 0; v < PER; ++v) {
        int i  = tid + v*THREADS;
        int i0 = base0 + i;
        float x0 = (i0 >= 0 && i0 < OUTLEN) ? nz[i0] : 0.0f;
        int i1 = i0 + HOP;
        float x1 = (i1 >= 0 && i1 < OUTLEN) ? nz[i1] : 0.0f;
        A[i] = make_float2(x0, x1);
    }
    // Filter bands for both frames: gf[0..127] frame t0, gf[128..255] frame t0+1
    {
        int f  = tid & (NBANDS-1);
        int fr = tid >> 7;
        gf[tid] = fb[((size_t)b*NBANDS + f)*TFRAMES + (t0 + fr)];
    }
    __syncthreads();

    // Forward FFT 3072 = 3 * 4^5  (Stockham, natural-order output)
    stage3(A, Bb, tid);            __syncthreads();
    stage4<1024,  3>(Bb, A, tid);  __syncthreads();
    stage4< 256, 12>(A, Bb, tid);  __syncthreads();
    stage4<  64, 48>(Bb, A, tid);  __syncthreads();
    stage4<  16,192>(A, Bb, tid);  __syncthreads();
    stage4<   4,768>(Bb, A, tid);  __syncthreads();
    // Z in A.

    // Spectrum multiply for both frames + conj (inverse-via-forward):
    // W[k] = a_k Z[k] + b_k conj(Z[N-k]);  store conj(W) into Bb.
    #pragma unroll
    for (int v = 0; v < PER; ++v) {
        int k = tid + v*THREADS;
        int j = (k <= HALF) ? k : (NFFT - k);   // symmetric bin index 0..1536
        float Gx = 0.0f, Gy = 0.0f;
        if (j != 0) {
            int band = (j - 1) / 12;            // 12 rfft bins per band
            Gx = gf[band];
            Gy = gf[NBANDS + band];
        }
        float ak = 0.5f*(Gx + Gy);
        float bk = 0.5f*(Gx - Gy);
        float2 Zk = A[k];
        int   kr  = k ? (NFFT - k) : 0;
        float2 Zr = A[kr];
        float wx = fmaf(ak, Zk.x,  bk*Zr.x);
        float wy = fmaf(ak, Zk.y, -bk*Zr.y);
        Bb[k] = make_float2(wx, -wy);           // conj(W)
    }
    __syncthreads();

    // Inverse FFT = conj(FFT(conj(W)))/N : run forward FFT on Bb
    stage3(Bb, A, tid);            __syncthreads();
    stage4<1024,  3>(A, Bb, tid);  __syncthreads();
    stage4< 256, 12>(Bb, A, tid);  __syncthreads();
    stage4<  64, 48>(A, Bb, tid);  __syncthreads();
    stage4<  16,192>(Bb, A, tid);  __syncthreads();
    stage4<   4,768>(A, Bb, tid);  __syncthreads();
    // U in Bb.  out_x = Re(U)/N, out_y = -Im(U)/N, then Hann window + overlap-add.

    const float invN = 1.0f / (float)NFFT;
    float* outb = out + (size_t)b * OUTLEN;
    #pragma unroll
    for (int v = 0; v < PER; ++v) {
        int n = tid + v*THREADS;
        float2 U = Bb[n];
        float h = 0.5f - 0.5f * __cosf(6.283185307179586f * (float)n / 3071.0f);
        float s = invN * h;
        float vx =  U.x * s;
        float vy = -U.y * s;
        int p0 = base0 + n;                 // output index for frame t0
        if (p0 >= 0 && p0 < OUTLEN) atomicAdd(&outb[p0], vx);
        int p1 = p0 + HOP;                  // frame t0+1
        if (p1 >= 0 && p1 < OUTLEN) atomicAdd(&outb[p1], vy);
    }
}

extern "C" void kernel_launch(void* const* d_in, const int* in_sizes, int n_in,
                              void* d_out, int out_size, void* d_ws, size_t ws_size,
                              hipStream_t stream)
{
    const float* fb    = (const float*)d_in[0];   // (8,1,128,1000) f32
    const float* noise = (const float*)d_in[1];   // (8,1,191808)   f32
    float* out = (float*)d_out;                   // (8,1,191808)   f32

    int B = in_sizes[1] / OUTLEN;                 // 8

    hipMemsetAsync(out, 0, (size_t)out_size * sizeof(float), stream);

    dim3 grid(B * (TFRAMES/2));                   // 4000 workgroups, 2 frames each
    filtered_noise_kernel<<<grid, THREADS, 0, stream>>>(fb, noise, out);
}

// Round 3
// 159.372 us; speedup vs baseline: 1.2623x; 1.2623x over previous
//
#include <hip/hip_runtime.h>

#define NFFT 3072
#define THREADS 256
#define HOP 192
#define HALF 1536
#define TFRAMES 1000
#define OUTLEN 191808
#define NBANDS 128
#define PI_F 3.14159265358979323846f

__device__ __forceinline__ float2 cadd(float2 a,float2 b){return make_float2(a.x+b.x,a.y+b.y);}
__device__ __forceinline__ float2 csub(float2 a,float2 b){return make_float2(a.x-b.x,a.y-b.y);}
__device__ __forceinline__ float2 cmul(float2 a,float2 b){
    return make_float2(fmaf(a.x,b.x,-a.y*b.y), fmaf(a.x,b.y,a.y*b.x));
}
__device__ __forceinline__ float2 cmuln_i(float2 a){return make_float2(a.y,-a.x);}  // a * (-i)
__device__ __forceinline__ float2 cneg(float2 a){return make_float2(-a.x,-a.y);}

// LDS padding: +1 float2 every 16 (128B) to break mod-16 bank aliasing
__device__ __forceinline__ int IDX(int i){ return i + (i>>4); }

__device__ __forceinline__ void dft4(float2 a0,float2 a1,float2 a2,float2 a3,
                                     float2&y0,float2&y1,float2&y2,float2&y3){
    float2 e0=cadd(a0,a2), e1=csub(a0,a2), o0=cadd(a1,a3), o1=csub(a1,a3);
    y0=cadd(e0,o0); y2=csub(e0,o0);
    float2 io=make_float2(-o1.y,o1.x);   // i*o1
    y1=csub(e1,io); y3=cadd(e1,io);
}
__device__ __forceinline__ void dft3(float2 a0,float2 a1,float2 a2,
                                     float2&y0,float2&y1,float2&y2){
    float2 s=cadd(a1,a2), d=csub(a1,a2);
    y0=cadd(a0,s);
    float2 t=make_float2(a0.x-0.5f*s.x, a0.y-0.5f*s.y);
    const float S3=0.86602540378443864676f;
    float2 id=make_float2(S3*d.y,-S3*d.x);   // -i*S3*d
    y1=cadd(t,id); y2=csub(t,id);
}

// 12-point DFT: o[j] = sum_l a[l] w12^{lj}.  12 = 4x3, n = 3*n1+n2, k = k1+4*k2
__device__ __forceinline__ void dft12(float2 a[12], float2 o[12]){
    float2 u[3][4];
    #pragma unroll
    for(int n2=0;n2<3;++n2)
        dft4(a[n2],a[3+n2],a[6+n2],a[9+n2],u[n2][0],u[n2][1],u[n2][2],u[n2][3]);
    const float2 W1=make_float2( 0.86602540378443865f,-0.5f);
    const float2 W2=make_float2( 0.5f,-0.86602540378443865f);
    const float2 W4=make_float2(-0.5f,-0.86602540378443865f);
    u[1][1]=cmul(u[1][1],W1); u[1][2]=cmul(u[1][2],W2); u[1][3]=cmuln_i(u[1][3]);
    u[2][1]=cmul(u[2][1],W2); u[2][2]=cmul(u[2][2],W4); u[2][3]=cneg(u[2][3]);
    #pragma unroll
    for(int k1=0;k1<4;++k1)
        dft3(u[0][k1],u[1][k1],u[2][k1], o[k1],o[k1+4],o[k1+8]);
}

// 16-point DFT: 16 = 4x4, n = 4*n1+n2, k = k1+4*k2
__device__ __forceinline__ void dft16(float2 a[16], float2 o[16]){
    float2 u[4][4];
    #pragma unroll
    for(int n2=0;n2<4;++n2)
        dft4(a[n2],a[4+n2],a[8+n2],a[12+n2],u[n2][0],u[n2][1],u[n2][2],u[n2][3]);
    const float C16=0.92387953251128674f, S16=0.38268343236508977f, R2=0.70710678118654752f;
    const float2 W1=make_float2( C16,-S16), W2=make_float2( R2,-R2), W3=make_float2( S16,-C16);
    const float2 W6=make_float2(-R2,-R2),  W9=make_float2(-C16, S16);
    u[1][1]=cmul(u[1][1],W1); u[1][2]=cmul(u[1][2],W2);   u[1][3]=cmul(u[1][3],W3);
    u[2][1]=cmul(u[2][1],W2); u[2][2]=cmuln_i(u[2][2]);   u[2][3]=cmul(u[2][3],W6);
    u[3][1]=cmul(u[3][1],W3); u[3][2]=cmul(u[3][2],W6);   u[3][3]=cmul(u[3][3],W9);
    #pragma unroll
    for(int k1=0;k1<4;++k1)
        dft4(u[0][k1],u[1][k1],u[2][k1],u[3][k1], o[k1],o[k1+4],o[k1+8],o[k1+12]);
}

// multiply o[j] *= w^j, w = e^{i*ang};  power tree
template<int R>
__device__ __forceinline__ void twiddle_pows(float2* o, float ang){
    float s,c; __sincosf(ang,&s,&c);
    float2 w1=make_float2(c,s);
    float2 w2=cmul(w1,w1);
    float2 w3=cmul(w2,w1);
    float2 w4=cmul(w2,w2);
    o[1]=cmul(o[1],w1); o[2]=cmul(o[2],w2); o[3]=cmul(o[3],w3);
    float2 w8=cmul(w4,w4);
    float2 w5=cmul(w4,w1), w6=cmul(w4,w2), w7=cmul(w4,w3);
    o[4]=cmul(o[4],w4); o[5]=cmul(o[5],w5); o[6]=cmul(o[6],w6); o[7]=cmul(o[7],w7);
    float2 w9=cmul(w8,w1), w10=cmul(w8,w2), w11=cmul(w8,w3);
    o[8]=cmul(o[8],w8); o[9]=cmul(o[9],w9); o[10]=cmul(o[10],w10); o[11]=cmul(o[11],w11);
    if constexpr (R>12){
        float2 w12=cmul(w8,w4), w13=cmul(w8,w5), w14=cmul(w8,w6), w15=cmul(w8,w7);
        o[12]=cmul(o[12],w12); o[13]=cmul(o[13],w13); o[14]=cmul(o[14],w14); o[15]=cmul(o[15],w15);
    }
}

// Stockham stage B: (NN=256, S=12, R=16).  reads q+12p+192l, writes q+192p+12j, twiddle w256^{p*j}
__device__ __forceinline__ void stageB(float2* A, int tid){
    const bool act = tid < 192;
    float2 o[16];
    int q=0,p=0;
    if(act){
        q = tid % 12; p = tid / 12;
        float2 a[16];
        int ib = IDX(q + 12*p);            // linear stride 192 -> padded stride 204
        #pragma unroll
        for(int l=0;l<16;++l) a[l] = A[ib + 204*l];
        dft16(a,o);
        twiddle_pows<16>(o, -2.0f*PI_F*(float)p*(1.0f/256.0f));
    }
    __syncthreads();
    if(act){
        #pragma unroll
        for(int j=0;j<16;++j) A[IDX(q + 192*p + 12*j)] = o[j];
    }
    __syncthreads();
}

__global__ __launch_bounds__(THREADS,4)
void filtered_noise_kernel(const float* __restrict__ fb,
                           const float* __restrict__ noise,
                           float* __restrict__ out)
{
    __shared__ float2 A[NFFT + NFFT/16];   // 3264 float2 = 26112 B
    __shared__ float gf[2*NBANDS];

    const int tid = threadIdx.x;
    const int wg  = blockIdx.x;
    const int b   = wg / (TFRAMES/2);
    const int tp  = wg % (TFRAMES/2);
    const int t0  = 2*tp;
    const float* nz = noise + (size_t)b * OUTLEN;
    const int base0 = t0*HOP - HALF;

    // filter gains: gf[0..127] frame t0, gf[128..255] frame t0+1
    gf[tid] = fb[((size_t)b*NBANDS + (tid & 127))*TFRAMES + t0 + (tid >> 7)];

    // ---- Phase 1: fwd stage A (NN=3072,S=1,R=12), global -> LDS ----
    {
        float2 a[12], o[12];
        #pragma unroll
        for(int l=0;l<12;++l){
            int i0 = base0 + tid + 256*l;
            float x0 = (i0 >= 0 && i0 < OUTLEN) ? nz[i0] : 0.0f;
            int i1 = i0 + HOP;
            float x1 = (i1 >= 0 && i1 < OUTLEN) ? nz[i1] : 0.0f;
            a[l] = make_float2(x0, x1);
        }
        dft12(a,o);
        twiddle_pows<12>(o, -2.0f*PI_F*(float)tid*(1.0f/3072.0f));
        #pragma unroll
        for(int j=0;j<12;++j) A[IDX(12*tid + j)] = o[j];
    }
    __syncthreads();

    // ---- Phase 2: fwd stage B ----
    stageB(A, tid);

    // ---- Phase 3: fwd stage C (NN=16,S=192,R=16, no twiddle), in-place ----
    {
        const bool act = tid < 192;
        float2 o[16];
        if(act){
            float2 a[16];
            int ib = IDX(tid);
            #pragma unroll
            for(int l=0;l<16;++l) a[l] = A[ib + 204*l];
            dft16(a,o);
        }
        __syncthreads();
        if(act){
            int ib = IDX(tid);
            #pragma unroll
            for(int j=0;j<16;++j) A[ib + 204*j] = o[j];
        }
        __syncthreads();
    }

    // ---- Phase 4: spectral multiply fused into inv stage A (R=12) ----
    // Z natural order: Z[k] at A[IDX(k)]; linear stride 256 -> padded stride 272.
    // W'[k] = conj(W[k]) = a_k*conj(Z[k]) + b_k*Z[N-k]
    {
        const int p = tid;
        float2 z[12], zm[12];
        {
            int ib = IDX(p);
            #pragma unroll
            for(int l=0;l<12;++l) z[l] = A[ib + 272*l];     // Z[p + 256*l]
        }
        {
            int pm = (p==0) ? 0 : (256 - p);
            int ib = IDX(pm);
            #pragma unroll
            for(int l=0;l<12;++l) zm[l] = A[ib + 272*l];    // Z[pm + 256*l]
        }
        float2 w[12];
        #pragma unroll
        for(int l=0;l<12;++l){
            int k = p + 256*l;
            int j = (k <= HALF) ? k : (NFFT - k);
            float aa = 0.0f, bb = 0.0f;
            if(j){
                int band = (j-1)/12;
                float Gx = gf[band], Gy = gf[NBANDS + band];
                aa = 0.5f*(Gx+Gy); bb = 0.5f*(Gx-Gy);
            }
            // Z[N-k]: N-k = (256-p) + 256*(11-l) for p>0; for p==0: 256*(12-l)
            float2 Zm = (p==0) ? ((l==0) ? z[0] : z[12-l]) : zm[11-l];
            w[l] = make_float2( fmaf(aa, z[l].x,  bb*Zm.x),
                                fmaf(-aa, z[l].y, bb*Zm.y) );
        }
        float2 o[12];
        dft12(w,o);
        twiddle_pows<12>(o, -2.0f*PI_F*(float)p*(1.0f/3072.0f));
        __syncthreads();                        // all reads done before writes
        #pragma unroll
        for(int j=0;j<12;++j) A[IDX(12*p + j)] = o[j];
        __syncthreads();
    }

    // ---- Phase 5: inv stage B ----
    stageB(A, tid);

    // ---- Phase 6: inv stage C fused with window + overlap-add (no barriers) ----
    {
        const bool act = tid < 192;
        if(act){
            float2 a[16], o[16];
            int ib = IDX(tid);
            #pragma unroll
            for(int l=0;l<16;++l) a[l] = A[ib + 204*l];
            dft16(a,o);
            const float invN = 1.0f/(float)NFFT;
            float* outb = out + (size_t)b * OUTLEN;
            #pragma unroll
            for(int j=0;j<16;++j){
                int n = tid + 192*j;
                float h = 0.5f - 0.5f*__cosf(2.0f*PI_F*(float)n*(1.0f/3071.0f));
                float s = invN*h;
                float vx =  o[j].x * s;
                float vy = -o[j].y * s;
                int p0 = base0 + n;
                if(p0 >= 0 && p0 < OUTLEN) atomicAdd(&outb[p0], vx);
                int p1 = p0 + HOP;
                if(p1 >= 0 && p1 < OUTLEN) atomicAdd(&outb[p1], vy);
            }
        }
    }
}

extern "C" void kernel_launch(void* const* d_in, const int* in_sizes, int n_in,
                              void* d_out, int out_size, void* d_ws, size_t ws_size,
                              hipStream_t stream)
{
    const float* fb    = (const float*)d_in[0];   // (8,1,128,1000) f32
    const float* noise = (const float*)d_in[1];   // (8,1,191808)   f32
    float* out = (float*)d_out;                   // (8,1,191808)   f32

    int B = in_sizes[1] / OUTLEN;                 // 8

    hipMemsetAsync(out, 0, (size_t)out_size * sizeof(float), stream);

    dim3 grid(B * (TFRAMES/2));                   // 4000 workgroups, 2 frames each
    filtered_noise_kernel<<<grid, THREADS, 0, stream>>>(fb, noise, out);
}

// Round 4
// 155.085 us; speedup vs baseline: 1.2972x; 1.0276x over previous
//
#include <hip/hip_runtime.h>

#define NFFT 3072
#define THREADS 256
#define HOP 192
#define HALF 1536
#define TFRAMES 1000
#define OUTLEN 191808
#define NBANDS 128
#define PI_F 3.14159265358979323846f
#define OLA_LEN 3456              // 3072 + 2*HOP (two merged frames)

__device__ __forceinline__ float2 cadd(float2 a,float2 b){return make_float2(a.x+b.x,a.y+b.y);}
__device__ __forceinline__ float2 csub(float2 a,float2 b){return make_float2(a.x-b.x,a.y-b.y);}
__device__ __forceinline__ float2 cmul(float2 a,float2 b){
    return make_float2(fmaf(a.x,b.x,-a.y*b.y), fmaf(a.x,b.y,a.y*b.x));
}
__device__ __forceinline__ float2 cmuln_i(float2 a){return make_float2(a.y,-a.x);}  // a * (-i)
__device__ __forceinline__ float2 cneg(float2 a){return make_float2(-a.x,-a.y);}

// LDS padding: +1 float2 every 16 (128B) to break mod-16 bank aliasing
__device__ __forceinline__ int IDX(int i){ return i + (i>>4); }

__device__ __forceinline__ void dft4(float2 a0,float2 a1,float2 a2,float2 a3,
                                     float2&y0,float2&y1,float2&y2,float2&y3){
    float2 e0=cadd(a0,a2), e1=csub(a0,a2), o0=cadd(a1,a3), o1=csub(a1,a3);
    y0=cadd(e0,o0); y2=csub(e0,o0);
    float2 io=make_float2(-o1.y,o1.x);   // i*o1
    y1=csub(e1,io); y3=cadd(e1,io);
}
__device__ __forceinline__ void dft3(float2 a0,float2 a1,float2 a2,
                                     float2&y0,float2&y1,float2&y2){
    float2 s=cadd(a1,a2), d=csub(a1,a2);
    y0=cadd(a0,s);
    float2 t=make_float2(a0.x-0.5f*s.x, a0.y-0.5f*s.y);
    const float S3=0.86602540378443864676f;
    float2 id=make_float2(S3*d.y,-S3*d.x);   // -i*S3*d
    y1=cadd(t,id); y2=csub(t,id);
}

// 12-point DFT: o[j] = sum_l a[l] w12^{lj}.  12 = 4x3
__device__ __forceinline__ void dft12(float2 a[12], float2 o[12]){
    float2 u[3][4];
    #pragma unroll
    for(int n2=0;n2<3;++n2)
        dft4(a[n2],a[3+n2],a[6+n2],a[9+n2],u[n2][0],u[n2][1],u[n2][2],u[n2][3]);
    const float2 W1=make_float2( 0.86602540378443865f,-0.5f);
    const float2 W2=make_float2( 0.5f,-0.86602540378443865f);
    const float2 W4=make_float2(-0.5f,-0.86602540378443865f);
    u[1][1]=cmul(u[1][1],W1); u[1][2]=cmul(u[1][2],W2); u[1][3]=cmuln_i(u[1][3]);
    u[2][1]=cmul(u[2][1],W2); u[2][2]=cmul(u[2][2],W4); u[2][3]=cneg(u[2][3]);
    #pragma unroll
    for(int k1=0;k1<4;++k1)
        dft3(u[0][k1],u[1][k1],u[2][k1], o[k1],o[k1+4],o[k1+8]);
}

// 16-point DFT: 16 = 4x4
__device__ __forceinline__ void dft16(float2 a[16], float2 o[16]){
    float2 u[4][4];
    #pragma unroll
    for(int n2=0;n2<4;++n2)
        dft4(a[n2],a[4+n2],a[8+n2],a[12+n2],u[n2][0],u[n2][1],u[n2][2],u[n2][3]);
    const float C16=0.92387953251128674f, S16=0.38268343236508977f, R2=0.70710678118654752f;
    const float2 W1=make_float2( C16,-S16), W2=make_float2( R2,-R2), W3=make_float2( S16,-C16);
    const float2 W6=make_float2(-R2,-R2),  W9=make_float2(-C16, S16);
    u[1][1]=cmul(u[1][1],W1); u[1][2]=cmul(u[1][2],W2);   u[1][3]=cmul(u[1][3],W3);
    u[2][1]=cmul(u[2][1],W2); u[2][2]=cmuln_i(u[2][2]);   u[2][3]=cmul(u[2][3],W6);
    u[3][1]=cmul(u[3][1],W3); u[3][2]=cmul(u[3][2],W6);   u[3][3]=cmul(u[3][3],W9);
    #pragma unroll
    for(int k1=0;k1<4;++k1)
        dft4(u[0][k1],u[1][k1],u[2][k1],u[3][k1], o[k1],o[k1+4],o[k1+8],o[k1+12]);
}

// multiply o[j] *= w^j, w = e^{i*ang};  power tree
template<int R>
__device__ __forceinline__ void twiddle_pows(float2* o, float ang){
    float s,c; __sincosf(ang,&s,&c);
    float2 w1=make_float2(c,s);
    float2 w2=cmul(w1,w1);
    float2 w3=cmul(w2,w1);
    float2 w4=cmul(w2,w2);
    o[1]=cmul(o[1],w1); o[2]=cmul(o[2],w2); o[3]=cmul(o[3],w3);
    float2 w8=cmul(w4,w4);
    float2 w5=cmul(w4,w1), w6=cmul(w4,w2), w7=cmul(w4,w3);
    o[4]=cmul(o[4],w4); o[5]=cmul(o[5],w5); o[6]=cmul(o[6],w6); o[7]=cmul(o[7],w7);
    float2 w9=cmul(w8,w1), w10=cmul(w8,w2), w11=cmul(w8,w3);
    o[8]=cmul(o[8],w8); o[9]=cmul(o[9],w9); o[10]=cmul(o[10],w10); o[11]=cmul(o[11],w11);
    if constexpr (R>12){
        float2 w12=cmul(w8,w4), w13=cmul(w8,w5), w14=cmul(w8,w6), w15=cmul(w8,w7);
        o[12]=cmul(o[12],w12); o[13]=cmul(o[13],w13); o[14]=cmul(o[14],w14); o[15]=cmul(o[15],w15);
    }
}

// Stockham stage B: (NN=256, S=12, R=16)
__device__ __forceinline__ void stageB(float2* A, int tid){
    const bool act = tid < 192;
    float2 o[16];
    int q=0,p=0;
    if(act){
        q = tid % 12; p = tid / 12;
        float2 a[16];
        int ib = IDX(q + 12*p);            // linear stride 192 -> padded 204
        #pragma unroll
        for(int l=0;l<16;++l) a[l] = A[ib + 204*l];
        dft16(a,o);
        twiddle_pows<16>(o, -2.0f*PI_F*(float)p*(1.0f/256.0f));
    }
    __syncthreads();
    if(act){
        #pragma unroll
        for(int j=0;j<16;++j) A[IDX(q + 192*p + 12*j)] = o[j];
    }
    __syncthreads();
}

__global__ __launch_bounds__(THREADS,4)
void filtered_noise_kernel(const float* __restrict__ fb,
                           const float* __restrict__ noise,
                           float* __restrict__ out)
{
    __shared__ float2 A[NFFT + NFFT/16];   // 3264 float2 = 26112 B
    __shared__ float gf[2*NBANDS];

    const int tid = threadIdx.x;
    // XCD-locality swizzle: grid = 4000 = 8 XCDs x 500. blockIdx%8 -> XCD (round
    // robin), so batch b = blockIdx&7 pins each batch's atomics + noise reads to
    // one XCD's L2 (working set ~2MB < 4MB).
    const int b   = blockIdx.x & 7;
    const int tp  = blockIdx.x >> 3;
    const int t0  = 2*tp;
    const float* nz = noise + (size_t)b * OUTLEN;
    const int base0 = t0*HOP - HALF;

    // filter gains: gf[0..127] frame t0, gf[128..255] frame t0+1
    gf[tid] = fb[((size_t)b*NBANDS + (tid & 127))*TFRAMES + t0 + (tid >> 7)];

    // ---- Phase 1: fwd stage A (NN=3072,S=1,R=12), global -> LDS ----
    {
        float2 a[12], o[12];
        #pragma unroll
        for(int l=0;l<12;++l){
            int i0 = base0 + tid + 256*l;
            float x0 = (i0 >= 0 && i0 < OUTLEN) ? nz[i0] : 0.0f;
            int i1 = i0 + HOP;
            float x1 = (i1 >= 0 && i1 < OUTLEN) ? nz[i1] : 0.0f;
            a[l] = make_float2(x0, x1);
        }
        dft12(a,o);
        twiddle_pows<12>(o, -2.0f*PI_F*(float)tid*(1.0f/3072.0f));
        #pragma unroll
        for(int j=0;j<12;++j) A[IDX(12*tid + j)] = o[j];
    }
    __syncthreads();

    // ---- Phase 2: fwd stage B ----
    stageB(A, tid);

    // ---- Phase 3: fwd stage C (NN=16,S=192,R=16, no twiddle), in-place ----
    {
        const bool act = tid < 192;
        float2 o[16];
        if(act){
            float2 a[16];
            int ib = IDX(tid);
            #pragma unroll
            for(int l=0;l<16;++l) a[l] = A[ib + 204*l];
            dft16(a,o);
        }
        __syncthreads();
        if(act){
            int ib = IDX(tid);
            #pragma unroll
            for(int j=0;j<16;++j) A[ib + 204*j] = o[j];
        }
        __syncthreads();
    }

    // ---- Phase 4: spectral multiply fused into inv stage A (R=12) ----
    // Z natural order: Z[k] at A[IDX(k)]; linear stride 256 -> padded 272.
    // W'[k] = conj(W[k]) = a_k*conj(Z[k]) + b_k*Z[N-k]
    {
        const int p = tid;
        float2 z[12], zm[12];
        {
            int ib = IDX(p);
            #pragma unroll
            for(int l=0;l<12;++l) z[l] = A[ib + 272*l];     // Z[p + 256*l]
        }
        {
            int pm = (p==0) ? 0 : (256 - p);
            int ib = IDX(pm);
            #pragma unroll
            for(int l=0;l<12;++l) zm[l] = A[ib + 272*l];    // Z[pm + 256*l]
        }
        float2 w[12];
        #pragma unroll
        for(int l=0;l<12;++l){
            int k = p + 256*l;
            int j = (k <= HALF) ? k : (NFFT - k);
            float aa = 0.0f, bb = 0.0f;
            if(j){
                int band = (j-1)/12;
                float Gx = gf[band], Gy = gf[NBANDS + band];
                aa = 0.5f*(Gx+Gy); bb = 0.5f*(Gx-Gy);
            }
            float2 Zm = (p==0) ? ((l==0) ? z[0] : z[12-l]) : zm[11-l];
            w[l] = make_float2( fmaf(aa, z[l].x,  bb*Zm.x),
                                fmaf(-aa, z[l].y, bb*Zm.y) );
        }
        float2 o[12];
        dft12(w,o);
        twiddle_pows<12>(o, -2.0f*PI_F*(float)p*(1.0f/3072.0f));
        __syncthreads();                        // all reads done before writes
        #pragma unroll
        for(int j=0;j<12;++j) A[IDX(12*p + j)] = o[j];
        __syncthreads();
    }

    // ---- Phase 5: inv stage B ----
    stageB(A, tid);

    // ---- Phase 6: inv stage C + window; merge both frames in LDS; coalesced OLA atomics ----
    {
        const bool act = tid < 192;
        float2 o[16];
        float vy[16];
        if(act){
            float2 a[16];
            int ib = IDX(tid);
            #pragma unroll
            for(int l=0;l<16;++l) a[l] = A[ib + 204*l];
            dft16(a,o);
        }
        __syncthreads();                 // all reads of A complete
        float* C = (float*)A;            // reuse LDS as float[OLA_LEN]
        // zero tail C[3072..3456) (vx pass below covers [0,3072))
        if (tid < 128){ C[3072+tid]=0.0f; C[3200+tid]=0.0f; C[3328+tid]=0.0f; }
        if(act){
            const float invN = 1.0f/(float)NFFT;
            #pragma unroll
            for(int j=0;j<16;++j){
                int n = tid + 192*j;
                float h = 0.5f - 0.5f*__cosf(2.0f*PI_F*(float)n*(1.0f/3071.0f));
                float s = invN*h;
                C[n]  =  o[j].x * s;     // frame t0, unique writer per n
                vy[j] = -o[j].y * s;     // frame t0+1, added next pass
            }
        }
        __syncthreads();
        if(act){
            #pragma unroll
            for(int j=0;j<16;++j){
                int n = tid + 192*j;
                C[n + HOP] += vy[j];     // unique writer per (n+192)
            }
        }
        __syncthreads();
        // 3456 combined samples -> coalesced global atomics (9 per output sample
        // across blocks, all L2-local thanks to the XCD swizzle)
        float* outb = out + (size_t)b * OUTLEN;
        #pragma unroll
        for(int j=0;j<14;++j){
            int c = tid + 256*j;
            if (c < OLA_LEN){
                int p0 = base0 + c;
                if (p0 >= 0 && p0 < OUTLEN) atomicAdd(&outb[p0], C[c]);
            }
        }
    }
}

extern "C" void kernel_launch(void* const* d_in, const int* in_sizes, int n_in,
                              void* d_out, int out_size, void* d_ws, size_t ws_size,
                              hipStream_t stream)
{
    const float* fb    = (const float*)d_in[0];   // (8,1,128,1000) f32
    const float* noise = (const float*)d_in[1];   // (8,1,191808)   f32
    float* out = (float*)d_out;                   // (8,1,191808)   f32

    int B = in_sizes[1] / OUTLEN;                 // 8

    hipMemsetAsync(out, 0, (size_t)out_size * sizeof(float), stream);

    dim3 grid(B * (TFRAMES/2));                   // 4000 workgroups, 2 frames each
    filtered_noise_kernel<<<grid, THREADS, 0, stream>>>(fb, noise, out);
}